// Round 19
// baseline (93.067 us; speedup 1.0000x reference)
//
#include <hip/hip_runtime.h>
#include <math.h>

typedef unsigned short u16;
typedef unsigned int u32;
typedef unsigned long long u64;
typedef _Float16 f16;
typedef __attribute__((ext_vector_type(8))) _Float16 half8;
typedef __attribute__((ext_vector_type(8))) short short8;
typedef __attribute__((ext_vector_type(4))) float f32x4;

#define CDIM 512
#define NTOK 4096
#define MTOK 1024
#define NHEAD 8

__device__ __forceinline__ u16 f2h(float x) {
  f16 h = (f16)x;
  return *(u16*)&h;
}

__device__ __forceinline__ void gload16(const void* g, void* l) {
  __builtin_amdgcn_global_load_lds(
      (const __attribute__((address_space(1))) u32*)g,
      (__attribute__((address_space(3))) u32*)l, 16, 0, 0);
}

// ==================== fragment-packing prep (fp16) ====================
// Frag (1024 B): packed[frag*512 + l*8 + j] = Mat[mt*16 + (l&15)][kt*32 + (l>>4)*8 + j],
// frag = mt*Kf + kt.
__global__ __launch_bounds__(256) void prep_pack(
    const float* __restrict__ Wq, const float* __restrict__ Wkv,
    const float* __restrict__ Wp, const float* __restrict__ Wsr,
    const float* __restrict__ x0, const float* __restrict__ x1,
    u16* __restrict__ WqTp, u16* __restrict__ WkvTp,
    u16* __restrict__ WpTp, u16* __restrict__ W2Tp,
    u16* __restrict__ xq, u16* __restrict__ xc) {
  const int b = blockIdx.x, t = threadIdx.x;
  const int fid = t >> 6, l = t & 63, lr = l & 15, lc = l >> 4;
  float v[8];
  u16* dp; size_t dst;
  if (b < 512) {
    const float* W; u16* op; int N, f;
    if (b < 128)      { W = Wq;  op = WqTp;  N = 512;  f = b * 4 + fid; }
    else if (b < 384) { W = Wkv; op = WkvTp; N = 1024; f = (b - 128) * 4 + fid; }
    else              { W = Wp;  op = WpTp;  N = 512;  f = (b - 384) * 4 + fid; }
    const int nt = f >> 4, kt = f & 15;
    const int n = nt * 16 + lr, k0 = kt * 32 + lc * 8;
#pragma unroll
    for (int j = 0; j < 8; ++j) v[j] = W[(size_t)(k0 + j) * N + n];
    dp = op; dst = (size_t)f * 512 + l * 8;
  } else if (b < 1024) {
    const int f = (b - 512) * 4 + fid;          // ot*64 + kt (2048 frags)
    const int ot = f >> 6, kt = f & 63;
    const int o = ot * 16 + lr;
    const int r0 = kt * 32 + lc * 8;
    const int p = r0 >> 9, i0 = r0 & 511;
#pragma unroll
    for (int j = 0; j < 8; ++j) v[j] = Wsr[(size_t)o * 2048 + (size_t)(i0 + j) * 4 + p];
    dp = W2Tp; dst = (size_t)f * 512 + l * 8;
  } else if (b < 3072) {
    const int g = (b - 1024) * 4 + fid;         // br(2) x mt(256) x kt(16)
    const int br = g >> 12, fl = g & 4095;
    const int mt = fl >> 4, kt = fl & 15;
    const float* x = br ? x1 : x0;
    const float* src = x + (size_t)(mt * 16 + lr) * 512 + kt * 32 + lc * 8;
#pragma unroll
    for (int j = 0; j < 8; ++j) v[j] = src[j];
    dp = xq; dst = (size_t)br * 2097152 + (size_t)fl * 512 + l * 8;
  } else {
    const int g = (b - 3072) * 4 + fid;         // br(2) x mt(64) x kt(64)
    const int br = g >> 12, fl = g & 4095;
    const int mt = fl >> 6, kt = fl & 63;
    const int m = mt * 16 + lr;
    const int p = kt >> 4, i0 = (kt * 32 + lc * 8) & 511;
    const int token = (((m >> 5) * 2 + (p >> 1)) << 6) + ((m & 31) * 2 + (p & 1));
    const float* x = br ? x1 : x0;
    const float* src = x + (size_t)token * 512 + i0;
#pragma unroll
    for (int j = 0; j < 8; ++j) v[j] = src[j];
    dp = xc; dst = (size_t)br * 2097152 + (size_t)fl * 512 + l * 8;
  }
  short8 hv;
#pragma unroll
  for (int j = 0; j < 8; ++j) hv[j] = (short)f2h(v[j]);
  *(short8*)&dp[dst] = hv;
}

// ==================== shared fp16 MFMA GEMM body (frag-packed, 2-buf dbuf) ====================
// modes: 0 = f32 at Of + obz*M*N
//        2 = f16(acc*oscale), FRAG-PACKED at Ob + br*M*N
//        3 = f16 kv split: col<512 -> Okf K-frag, col>=512 -> Ovf V^T-frag
__device__ __forceinline__ void gemm_body(
    const u16* __restrict__ A, const u16* __restrict__ BT,
    int Kf, int ktiles, int kt0, int row0, int col0,
    int mode, int M, int N, int obz, int br,
    float* __restrict__ Of, u16* __restrict__ Ob,
    u16* __restrict__ Okf, u16* __restrict__ Ovf, float oscale,
    u16 (*sA)[2048], u16 (*sB)[2048]) {
  const int t = threadIdx.x;
  const int w = t >> 6;
  const int l = t & 63;
  const int lr = l & 15;
  const int lc = l >> 4;

  const size_t abase = (size_t)((row0 >> 4) + w) * Kf * 512 + (size_t)l * 8;
  const size_t bbase = (size_t)((col0 >> 4) + w) * Kf * 512 + (size_t)l * 8;

  f32x4 acc[2][2];
#pragma unroll
  for (int a = 0; a < 2; ++a)
#pragma unroll
    for (int b2 = 0; b2 < 2; ++b2) acc[a][b2] = (f32x4){0.f, 0.f, 0.f, 0.f};

  const int wr = (w >> 1) * 2;
  const int wc = (w & 1) * 2;

  gload16(A + abase + (size_t)kt0 * 512, (void*)&sA[0][w * 512]);
  gload16(BT + bbase + (size_t)kt0 * 512, (void*)&sB[0][w * 512]);
  __syncthreads();

  int cur = 0;
  for (int ti = 0; ti < ktiles; ++ti) {
    if (ti + 1 < ktiles) {
      gload16(A + abase + (size_t)(kt0 + ti + 1) * 512, (void*)&sA[cur ^ 1][w * 512]);
      gload16(BT + bbase + (size_t)(kt0 + ti + 1) * 512, (void*)&sB[cur ^ 1][w * 512]);
    }

    half8 a[2], b[2];
#pragma unroll
    for (int i = 0; i < 2; ++i) {
      a[i] = *(const half8*)&sA[cur][(wr + i) * 512 + l * 8];
      b[i] = *(const half8*)&sB[cur][(wc + i) * 512 + l * 8];
    }
#pragma unroll
    for (int mt = 0; mt < 2; ++mt)
#pragma unroll
      for (int nt2 = 0; nt2 < 2; ++nt2)
        acc[mt][nt2] = __builtin_amdgcn_mfma_f32_16x16x32_f16(a[mt], b[nt2], acc[mt][nt2], 0, 0, 0);
    __syncthreads();
    cur ^= 1;
  }

  const int rowb = row0 + (w >> 1) * 32;
  const int colb = col0 + (w & 1) * 32;
#pragma unroll
  for (int mt = 0; mt < 2; ++mt)
#pragma unroll
    for (int nt2 = 0; nt2 < 2; ++nt2) {
      const int col = colb + nt2 * 16 + lr;
#pragma unroll
      for (int j = 0; j < 4; ++j) {
        const int row = rowb + mt * 16 + lc * 4 + j;
        float v = acc[mt][nt2][j];
        if (mode == 0) {
          Of[(size_t)obz * M * N + (size_t)row * N + col] = v;
        } else if (mode == 2) {
          const size_t frag = (size_t)(row >> 4) * (N >> 5) + (col >> 5);
          const size_t dst = (size_t)br * M * N + frag * 512 +
                             (((col >> 3) & 3) * 16 + (row & 15)) * 8 + (col & 7);
          Ob[dst] = f2h(v * oscale);
        } else {  // mode 3: kv -> kf / vf fragment layouts
          const u16 hv = f2h(v);
          if (col < 512) {
            const int h = col >> 6, d = col & 63;
            const size_t dst = (size_t)br * 524288 + (size_t)h * 65536 +
                ((size_t)(row >> 4) * 2 + (d >> 5)) * 512 +
                ((row & 15) + 16 * ((d >> 3) & 3)) * 8 + (d & 7);
            Okf[dst] = hv;
          } else {
            const int c = col - 512;
            const int h = c >> 6, d = c & 63;
            const size_t dst = (size_t)br * 524288 + (size_t)h * 65536 +
                ((size_t)(row >> 5) * 4 + (d >> 4)) * 512 +
                ((d & 15) + 16 * ((row >> 3) & 3)) * 8 + (row & 7);
            Ovf[dst] = hv;
          }
        }
      }
    }
}

// ==================== gemm_sp kernel (kv projection) ====================
__global__ __launch_bounds__(256) void gemm_sp(
    const u16* __restrict__ A0, const u16* __restrict__ A1,
    const u16* __restrict__ BT,
    int M, int N, int Kf, int ktiles, int nk, int mode,
    float* __restrict__ Of, u16* __restrict__ Ob,
    u16* __restrict__ Okf, u16* __restrict__ Ovf, float oscale) {
  __shared__ u16 sA[2][2048], sB[2][2048];
  const int nwx = gridDim.x, nwy = gridDim.y;
  const int total = nwx * nwy * gridDim.z;
  const int L = blockIdx.x + nwx * (blockIdx.y + nwy * blockIdx.z);
  const int chunk = total >> 3;
  int W = (L & 7) * chunk + (L >> 3);
  const int wx = W % nwx; W /= nwx;
  const int wy = W % nwy;
  const int bz = W / nwy;
  const int br = bz / nk, kcid = bz % nk;
  gemm_body(br ? A1 : A0, BT, Kf, ktiles, kcid * ktiles, wy * 64, wx * 64,
            mode, M, N, bz, br, Of, Ob, Okf, Ovf, oscale, sA, sB);
}

// ==================== fused conv (split-K=4) + qproj (one launch; outputs DISJOINT) ====================
__global__ __launch_bounds__(256) void qc_fused(
    const u16* __restrict__ xc, const u16* __restrict__ W2Tp,
    const u16* __restrict__ xq, const u16* __restrict__ WqTp,
    float* __restrict__ xr, u16* __restrict__ qb2, float qscale) {
  __shared__ u16 sA[2][2048], sB[2][2048];
  if (blockIdx.x < 1024) {
    // SR conv as packed GEMM, split-K=4 -> f32 partials
    const int L = blockIdx.x;
    int W = (L & 7) * 128 + (L >> 3);
    const int wx = W % 8; W /= 8;
    const int wy = W % 16;
    const int bz = W / 16;           // br*4 + kcid
    const int br = bz >> 2, kcid = bz & 3;
    gemm_body(br ? xc + 2097152 : xc, W2Tp, 64, 16, kcid * 16, wy * 64, wx * 64,
              0, 1024, 512, bz, br, xr, nullptr, nullptr, nullptr, 1.0f, sA, sB);
  } else {
    // q projection -> FRAG-PACKED fp16 q (pre-scaled)
    const int L = blockIdx.x - 1024;
    int W = (L & 7) * 128 + (L >> 3);
    const int wx = W % 8; W /= 8;
    const int wy = W % 64;
    const int br = W / 64;
    gemm_body(br ? xq + 2097152 : xq, WqTp, 16, 16, 0, wy * 64, wx * 64,
              2, 4096, 512, br, br, nullptr, qb2, nullptr, nullptr, qscale, sA, sB);
  }
}

// ==================== out-proj + bias + mask + predicated token exchange ====================
__global__ __launch_bounds__(256) void gemm_out(
    const u16* __restrict__ Ap, const u16* __restrict__ Bp,
    const float* __restrict__ bias,
    const float* __restrict__ mask0, const float* __restrict__ mask1,
    float* __restrict__ out) {
  __shared__ u16 sA[2][2048], sB[2][2048];
  const int t = threadIdx.x;
  const int w = t >> 6;
  const int l = t & 63;
  const int lr = l & 15;
  const int lc = l >> 4;

  // XCD swizzle over (8,64,2) = 1024 blocks
  const int L = blockIdx.x + 8 * (blockIdx.y + 64 * blockIdx.z);
  int W = (L & 7) * 128 + (L >> 3);
  const int wx = W % 8; W /= 8;
  const int wy = W % 64;
  const int br = W / 64;

  const int row0 = wy * 64;
  const int col0 = wx * 64;
  const int Kf = 16;
  const u16* A = Ap + (size_t)br * 2097152;

  const size_t abase = (size_t)((row0 >> 4) + w) * Kf * 512 + (size_t)l * 8;
  const size_t bbase = (size_t)((col0 >> 4) + w) * Kf * 512 + (size_t)l * 8;

  f32x4 acc[2][2];
#pragma unroll
  for (int a = 0; a < 2; ++a)
#pragma unroll
    for (int b2 = 0; b2 < 2; ++b2) acc[a][b2] = (f32x4){0.f, 0.f, 0.f, 0.f};

  const int wr = (w >> 1) * 2;
  const int wc = (w & 1) * 2;

  gload16(A + abase, (void*)&sA[0][w * 512]);
  gload16(Bp + bbase, (void*)&sB[0][w * 512]);
  __syncthreads();

  int cur = 0;
  for (int ti = 0; ti < 16; ++ti) {
    if (ti + 1 < 16) {
      gload16(A + abase + (size_t)(ti + 1) * 512, (void*)&sA[cur ^ 1][w * 512]);
      gload16(Bp + bbase + (size_t)(ti + 1) * 512, (void*)&sB[cur ^ 1][w * 512]);
    }
    half8 a[2], b[2];
#pragma unroll
    for (int i = 0; i < 2; ++i) {
      a[i] = *(const half8*)&sA[cur][(wr + i) * 512 + l * 8];
      b[i] = *(const half8*)&sB[cur][(wc + i) * 512 + l * 8];
    }
#pragma unroll
    for (int mt = 0; mt < 2; ++mt)
#pragma unroll
      for (int nt2 = 0; nt2 < 2; ++nt2)
        acc[mt][nt2] = __builtin_amdgcn_mfma_f32_16x16x32_f16(a[mt], b[nt2], acc[mt][nt2], 0, 0, 0);
    __syncthreads();
    cur ^= 1;
  }

  const float* mk = br ? mask1 : mask0;   // own mask
  const float* mo = br ? mask0 : mask1;   // other branch's mask
  float* myout = out + (size_t)br * 2097152;
  float* otout = out + (size_t)(br ^ 1) * 2097152;

  const int rowb = row0 + (w >> 1) * 32;
  const int colb = col0 + (w & 1) * 32;
#pragma unroll
  for (int mt = 0; mt < 2; ++mt)
#pragma unroll
    for (int nt2 = 0; nt2 < 2; ++nt2) {
      const int col = colb + nt2 * 16 + lr;
      const float bv = bias[col];
#pragma unroll
      for (int j = 0; j < 4; ++j) {
        const int row = rowb + mt * 16 + lc * 4 + j;
        const float mv = mk[row];
        const float o = (acc[mt][nt2][j] + bv) * mv;
        if (mv >= 0.02f) myout[(size_t)row * 512 + col] = o;
        if (mo[row] < 0.02f) otout[(size_t)row * 512 + col] = o;
      }
    }
}

// ==================== LayerNorm: sum 4 conv partials + bsr -> frag-packed fp16 ====================
__global__ __launch_bounds__(256) void ln_split(const float* __restrict__ xr,
                                                const float* __restrict__ bsr,
                                                const float* __restrict__ gamma,
                                                const float* __restrict__ beta,
                                                u16* __restrict__ xnp) {
  const int row = blockIdx.x;
  const int br = blockIdx.y;
  const int t = threadIdx.x;
  const float* p = xr + (size_t)br * 4 * 524288 + (size_t)row * 512;
  const int c = t * 2;
  float v0 = p[c] + p[524288 + c] + p[1048576 + c] + p[1572864 + c] + bsr[c];
  float v1 = p[c + 1] + p[524288 + c + 1] + p[1048576 + c + 1] + p[1572864 + c + 1] + bsr[c + 1];
  float s = v0 + v1, sq = v0 * v0 + v1 * v1;
#pragma unroll
  for (int m = 1; m < 64; m <<= 1) {
    s += __shfl_xor(s, m, 64);
    sq += __shfl_xor(sq, m, 64);
  }
  __shared__ float ls[4], lsq[4];
  __shared__ float ybuf[512];
  if ((t & 63) == 0) { ls[t >> 6] = s; lsq[t >> 6] = sq; }
  __syncthreads();
  s = ls[0] + ls[1] + ls[2] + ls[3];
  sq = lsq[0] + lsq[1] + lsq[2] + lsq[3];
  float mean = s * (1.0f / 512.0f);
  float var = sq * (1.0f / 512.0f) - mean * mean;
  float rs = rsqrtf(var + 1e-5f);
  ybuf[c] = (v0 - mean) * rs * gamma[c] + beta[c];
  ybuf[c + 1] = (v1 - mean) * rs * gamma[c + 1] + beta[c + 1];
  __syncthreads();
  if (t < 64) {
    const int c0 = t * 8;
    const int kt = c0 >> 5, lcf = (c0 >> 3) & 3, lrf = row & 15;
    const size_t dst = (size_t)br * 524288 +
        ((size_t)(row >> 4) * 16 + kt) * 512 + (lcf * 16 + lrf) * 8;
    short8 o8;
#pragma unroll
    for (int j = 0; j < 8; ++j) o8[j] = (short)f2h(ybuf[c0 + j]);
    *(short8*)&xnp[dst] = o8;
  }
}

// ==================== fp16 MFMA flash attention (64 q/block, 4-way KV split) ====================
// Register-pipelined: K frags double-buffered across tiles (kcA/kcB), V frags
// issued at body top so their latency hides under QK^T + softmax.
__global__ __launch_bounds__(256) void attn_mfma(const u16* __restrict__ qb,
                                                 const u16* __restrict__ kf,
                                                 const u16* __restrict__ vf,
                                                 u16* __restrict__ aop) {
  const int t = threadIdx.x;
  const int w = t >> 6;
  const int l = t & 63;
  const int lr = l & 15;
  const int lc = l >> 4;
  const int hh = blockIdx.y;
  const int n0 = blockIdx.x * 64;
  const int br = blockIdx.z;
  qb += (size_t)br * 2097152;
  kf += (size_t)br * 524288 + (size_t)hh * 65536;
  vf += (size_t)br * 524288 + (size_t)hh * 65536;
  aop += (size_t)br * 2097152;

  // union: P [4 waves][64 q][72 kv] u16 (loop) / Osum [4][32 d][66 q] f32 (combine pass)
  __shared__ __align__(16) u16 SH[18944];          // 37888 B
  u16* Pw = &SH[w * 4608];
  float* Osum = (float*)SH;                         // 33792 B per pass
  float* Lsum = (float*)(SH + 18432);               // byte 36864, [4][64] f32

  // Q^T B-fragments: frag = ((n0>>4)+qh)*16 + hh*2 + ks
  half8 bq[4][2];
#pragma unroll
  for (int qh = 0; qh < 4; ++qh)
#pragma unroll
    for (int ks = 0; ks < 2; ++ks)
      bq[qh][ks] = *(const half8*)&qb[
          (size_t)(((n0 >> 4) + qh) * 16 + hh * 2 + ks) * 512 + l * 8];

  f32x4 acc[4][4];   // [db][qh]
#pragma unroll
  for (int a = 0; a < 4; ++a)
#pragma unroll
    for (int b = 0; b < 4; ++b) acc[a][b] = (f32x4){0.f, 0.f, 0.f, 0.f};
  float lsum[4] = {0.f, 0.f, 0.f, 0.f};

  const size_t lofs = (size_t)l * 8;
  half8 kcA[8], kcB[8], av[8];

  // prologue: K frags for tile 0
  {
    const u16* kt0p = kf + (size_t)((w * 256) >> 4) * 1024;
#pragma unroll
    for (int f = 0; f < 8; ++f)
      kcA[f] = *(const half8*)&kt0p[(size_t)f * 512 + lofs];
  }

#define ATTN_TILE(IT, KC_CUR, KC_NXT, PREFETCH)                                     \
  {                                                                                 \
    const int m0 = w * 256 + (IT) * 64;                                             \
    const u16* vtile = vf + (size_t)(m0 >> 5) * 2048;                               \
    _Pragma("unroll")                                                               \
    for (int f = 0; f < 8; ++f)                                                     \
      av[f] = *(const half8*)&vtile[(size_t)f * 512 + lofs];                        \
    if (PREFETCH) {                                                                 \
      const u16* ktn = kf + (size_t)((m0 + 64) >> 4) * 1024;                        \
      _Pragma("unroll")                                                             \
      for (int f = 0; f < 8; ++f)                                                   \
        KC_NXT[f] = *(const half8*)&ktn[(size_t)f * 512 + lofs];                    \
    }                                                                               \
    _Pragma("unroll")                                                               \
    for (int f = 0; f < 4; ++f) {                                                   \
      f32x4 st[4];                                                                  \
      __builtin_amdgcn_s_setprio(1);                                                \
      _Pragma("unroll")                                                             \
      for (int qh = 0; qh < 4; ++qh) {                                              \
        f32x4 s = (f32x4){0.f, 0.f, 0.f, 0.f};                                      \
        s = __builtin_amdgcn_mfma_f32_16x16x32_f16(KC_CUR[f * 2 + 0], bq[qh][0], s, 0, 0, 0); \
        s = __builtin_amdgcn_mfma_f32_16x16x32_f16(KC_CUR[f * 2 + 1], bq[qh][1], s, 0, 0, 0); \
        st[qh] = s;                                                                 \
      }                                                                             \
      __builtin_amdgcn_s_setprio(0);                                                \
      _Pragma("unroll")                                                             \
      for (int qh = 0; qh < 4; ++qh) {                                              \
        float p0, p1, p2, p3;                                                       \
        asm("v_exp_f32 %0, %1" : "=v"(p0) : "v"(st[qh][0]));                        \
        asm("v_exp_f32 %0, %1" : "=v"(p1) : "v"(st[qh][1]));                        \
        asm("v_exp_f32 %0, %1" : "=v"(p2) : "v"(st[qh][2]));                        \
        asm("v_exp_f32 %0, %1" : "=v"(p3) : "v"(st[qh][3]));                        \
        lsum[qh] += (p0 + p1) + (p2 + p3);                                          \
        auto ha = __builtin_amdgcn_cvt_pkrtz(p0, p1);                               \
        auto hb = __builtin_amdgcn_cvt_pkrtz(p2, p3);                               \
        uint2 pk; pk.x = __builtin_bit_cast(u32, ha); pk.y = __builtin_bit_cast(u32, hb); \
        *(uint2*)&Pw[(qh * 16 + lr) * 72 + f * 16 + lc * 4] = pk;                   \
      }                                                                             \
    }                                                                               \
    _Pragma("unroll")                                                               \
    for (int ks = 0; ks < 2; ++ks) {                                                \
      _Pragma("unroll")                                                             \
      for (int qh = 0; qh < 4; ++qh) {                                              \
        half8 bp = *(const half8*)&Pw[(qh * 16 + lr) * 72 + ks * 32 + lc * 8];      \
        __builtin_amdgcn_s_setprio(1);                                              \
        _Pragma("unroll")                                                           \
        for (int db = 0; db < 4; ++db)                                              \
          acc[db][qh] = __builtin_amdgcn_mfma_f32_16x16x32_f16(av[ks * 4 + db], bp, acc[db][qh], 0, 0, 0); \
        __builtin_amdgcn_s_setprio(0);                                              \
      }                                                                             \
    }                                                                               \
  }

  ATTN_TILE(0, kcA, kcB, 1)
  ATTN_TILE(1, kcB, kcA, 1)
  ATTN_TILE(2, kcA, kcB, 1)
  ATTN_TILE(3, kcB, kcA, 0)
#undef ATTN_TILE

#pragma unroll
  for (int qh = 0; qh < 4; ++qh) {
    lsum[qh] += __shfl_xor(lsum[qh], 16, 64);
    lsum[qh] += __shfl_xor(lsum[qh], 32, 64);
  }

  // two-pass combine over d halves (Osum overlays P; Lsum is above Osum region)
#pragma unroll
  for (int pass = 0; pass < 2; ++pass) {
    __syncthreads();   // P reads (or prev pass combine reads) done
#pragma unroll
    for (int db2 = 0; db2 < 2; ++db2) {
      const int db = pass * 2 + db2;
#pragma unroll
      for (int qh = 0; qh < 4; ++qh)
#pragma unroll
        for (int j = 0; j < 4; ++j)
          Osum[((size_t)w * 32 + db2 * 16 + lc * 4 + j) * 66 + (qh * 16 + lr)] = acc[db][qh][j];
    }
    if (pass == 0 && lc == 0) {
#pragma unroll
      for (int qh = 0; qh < 4; ++qh) Lsum[w * 64 + qh * 16 + lr] = lsum[qh];
    }
    __syncthreads();

    const int q = t & 63;
    const int dd = (t >> 6) * 8;    // 8 d per thread within pass
    const float linv = 1.0f / (Lsum[q] + Lsum[64 + q] + Lsum[128 + q] + Lsum[192 + q]);
    short8 hv;
#pragma unroll
    for (int i = 0; i < 8; ++i) {
      const int drow = dd + i;
      float v = (Osum[drow * 66 + q] + Osum[(32 + drow) * 66 + q] +
                 Osum[(64 + drow) * 66 + q] + Osum[(96 + drow) * 66 + q]) * linv;
      hv[i] = (short)f2h(v);
    }
    const int mrow = n0 + q;
    const int kcoord = hh * 64 + pass * 32 + dd;
    const size_t dst = ((size_t)(mrow >> 4) * 16 + (kcoord >> 5)) * 512 +
                       (((kcoord >> 3) & 3) * 16 + (mrow & 15)) * 8;
    *(short8*)&aop[dst] = hv;
  }
}

extern "C" void kernel_launch(void* const* d_in, const int* in_sizes, int n_in,
                              void* d_out, int out_size, void* d_ws, size_t ws_size,
                              hipStream_t stream) {
  const float* x0    = (const float*)d_in[0];
  const float* x1    = (const float*)d_in[1];
  const float* mask0 = (const float*)d_in[2];
  const float* mask1 = (const float*)d_in[3];
  const float* Wq    = (const float*)d_in[4];
  const float* Wkv   = (const float*)d_in[5];
  const float* Wsr   = (const float*)d_in[6];
  const float* bsr   = (const float*)d_in[7];
  const float* gamma = (const float*)d_in[8];
  const float* beta  = (const float*)d_in[9];
  const float* Wp    = (const float*)d_in[10];
  const float* bp    = (const float*)d_in[11];

  u16* U = (u16*)d_ws;
  u16* WqTp  = U;                      // 262144
  u16* WkvTp = WqTp + 262144;          // 524288
  u16* WpTp  = WkvTp + 524288;         // 262144
  u16* W2Tp  = WpTp + 262144;          // 1048576
  u16* xq    = W2Tp + 1048576;         // 4194304 (2 br, stride 2097152)
  u16* xc    = xq + 4194304;           // 4194304 (2 br; xn reuses [0,1048576) after conv)
  u16* R     = xc + 4194304;           // xr f32 region
  float* xr  = (float*)R;              // 4194304 f32 (2 br x 4 parts x 524288)
  u16* qb2   = R + 8388608;            // 4194304 — DISJOINT from xr (qc_fused concurrent)
  u16* kf    = qb2 + 4194304;          // 1048576 (2 br, stride 524288)
  u16* vf    = kf + 1048576;           // 1048576
  u16* aop   = xq;                     // alias (xq dead after qproj)

  float* out = (float*)d_out;
  dim3 blk(256);

  // fragment-packing prep (weights + x in q-proj and conv-gather orders)
  prep_pack<<<5120, blk, 0, stream>>>(Wq, Wkv, Wp, Wsr, x0, x1,
      WqTp, WkvTp, WpTp, W2Tp, xq, xc);

  // fused: SR conv (split-K=4 -> f32 partials) + q projection (frag-packed fp16)
  qc_fused<<<2048, blk, 0, stream>>>(xc, W2Tp, xq, WqTp, xr, qb2,
      0.125f * 1.4426950408889634f);

  // LayerNorm (+bsr) -> frag-packed fp16 into xc (conv input dead)
  ln_split<<<dim3(1024, 2), blk, 0, stream>>>(xr, bsr, gamma, beta, xc);

  // kv projection -> kf/vf fragment layouts DIRECTLY
  gemm_sp<<<dim3(16, 16, 2), blk, 0, stream>>>(xc, xc + 524288, WkvTp,
      1024, 1024, 16, 16, 1, 3, nullptr, nullptr, kf, vf, 1.0f);

  // attention (64 q/block, 4-way KV split, register-pipelined K/V) -> aop frag-packed
  attn_mfma<<<dim3(64, 8, 2), blk, 0, stream>>>(qb2, kf, vf, aop);

  // out-proj + bias + mask + predicated token exchange (1 branch/block, 1024 blocks)
  gemm_out<<<dim3(8, 64, 2), blk, 0, stream>>>(aop, WpTp, bp, mask0, mask1, out);
}

// Round 20
// 92.276 us; speedup vs baseline: 1.0086x; 1.0086x over previous
//
#include <hip/hip_runtime.h>
#include <math.h>

typedef unsigned short u16;
typedef unsigned int u32;
typedef unsigned long long u64;
typedef _Float16 f16;
typedef __attribute__((ext_vector_type(8))) _Float16 half8;
typedef __attribute__((ext_vector_type(8))) short short8;
typedef __attribute__((ext_vector_type(4))) float f32x4;

#define CDIM 512
#define NTOK 4096
#define MTOK 1024
#define NHEAD 8

__device__ __forceinline__ u16 f2h(float x) {
  f16 h = (f16)x;
  return *(u16*)&h;
}

__device__ __forceinline__ void gload16(const void* g, void* l) {
  __builtin_amdgcn_global_load_lds(
      (const __attribute__((address_space(1))) u32*)g,
      (__attribute__((address_space(3))) u32*)l, 16, 0, 0);
}

// ==================== fragment-packing prep (fp16) ====================
// Frag (1024 B): packed[frag*512 + l*8 + j] = Mat[mt*16 + (l&15)][kt*32 + (l>>4)*8 + j],
// frag = mt*Kf + kt.
__global__ __launch_bounds__(256) void prep_pack(
    const float* __restrict__ Wq, const float* __restrict__ Wkv,
    const float* __restrict__ Wp, const float* __restrict__ Wsr,
    const float* __restrict__ x0, const float* __restrict__ x1,
    u16* __restrict__ WqTp, u16* __restrict__ WkvTp,
    u16* __restrict__ WpTp, u16* __restrict__ W2Tp,
    u16* __restrict__ xq, u16* __restrict__ xc) {
  const int b = blockIdx.x, t = threadIdx.x;
  const int fid = t >> 6, l = t & 63, lr = l & 15, lc = l >> 4;
  float v[8];
  u16* dp; size_t dst;
  if (b < 512) {
    const float* W; u16* op; int N, f;
    if (b < 128)      { W = Wq;  op = WqTp;  N = 512;  f = b * 4 + fid; }
    else if (b < 384) { W = Wkv; op = WkvTp; N = 1024; f = (b - 128) * 4 + fid; }
    else              { W = Wp;  op = WpTp;  N = 512;  f = (b - 384) * 4 + fid; }
    const int nt = f >> 4, kt = f & 15;
    const int n = nt * 16 + lr, k0 = kt * 32 + lc * 8;
#pragma unroll
    for (int j = 0; j < 8; ++j) v[j] = W[(size_t)(k0 + j) * N + n];
    dp = op; dst = (size_t)f * 512 + l * 8;
  } else if (b < 1024) {
    const int f = (b - 512) * 4 + fid;          // ot*64 + kt (2048 frags)
    const int ot = f >> 6, kt = f & 63;
    const int o = ot * 16 + lr;
    const int r0 = kt * 32 + lc * 8;
    const int p = r0 >> 9, i0 = r0 & 511;
#pragma unroll
    for (int j = 0; j < 8; ++j) v[j] = Wsr[(size_t)o * 2048 + (size_t)(i0 + j) * 4 + p];
    dp = W2Tp; dst = (size_t)f * 512 + l * 8;
  } else if (b < 3072) {
    const int g = (b - 1024) * 4 + fid;         // br(2) x mt(256) x kt(16)
    const int br = g >> 12, fl = g & 4095;
    const int mt = fl >> 4, kt = fl & 15;
    const float* x = br ? x1 : x0;
    const float* src = x + (size_t)(mt * 16 + lr) * 512 + kt * 32 + lc * 8;
#pragma unroll
    for (int j = 0; j < 8; ++j) v[j] = src[j];
    dp = xq; dst = (size_t)br * 2097152 + (size_t)fl * 512 + l * 8;
  } else {
    const int g = (b - 3072) * 4 + fid;         // br(2) x mt(64) x kt(64)
    const int br = g >> 12, fl = g & 4095;
    const int mt = fl >> 6, kt = fl & 63;
    const int m = mt * 16 + lr;
    const int p = kt >> 4, i0 = (kt * 32 + lc * 8) & 511;
    const int token = (((m >> 5) * 2 + (p >> 1)) << 6) + ((m & 31) * 2 + (p & 1));
    const float* x = br ? x1 : x0;
    const float* src = x + (size_t)token * 512 + i0;
#pragma unroll
    for (int j = 0; j < 8; ++j) v[j] = src[j];
    dp = xc; dst = (size_t)br * 2097152 + (size_t)fl * 512 + l * 8;
  }
  short8 hv;
#pragma unroll
  for (int j = 0; j < 8; ++j) hv[j] = (short)f2h(v[j]);
  *(short8*)&dp[dst] = hv;
}

// ==================== shared fp16 MFMA GEMM body (frag-packed, 2-buf dbuf) ====================
// modes: 0 = f32 at Of + obz*M*N
//        2 = f16(acc*oscale), FRAG-PACKED at Ob + br*M*N
//        3 = f16 kv split: col<512 -> Okf K-frag, col>=512 -> Ovf V^T-frag
__device__ __forceinline__ void gemm_body(
    const u16* __restrict__ A, const u16* __restrict__ BT,
    int Kf, int ktiles, int kt0, int row0, int col0,
    int mode, int M, int N, int obz, int br,
    float* __restrict__ Of, u16* __restrict__ Ob,
    u16* __restrict__ Okf, u16* __restrict__ Ovf, float oscale,
    u16 (*sA)[2048], u16 (*sB)[2048]) {
  const int t = threadIdx.x;
  const int w = t >> 6;
  const int l = t & 63;
  const int lr = l & 15;
  const int lc = l >> 4;

  const size_t abase = (size_t)((row0 >> 4) + w) * Kf * 512 + (size_t)l * 8;
  const size_t bbase = (size_t)((col0 >> 4) + w) * Kf * 512 + (size_t)l * 8;

  f32x4 acc[2][2];
#pragma unroll
  for (int a = 0; a < 2; ++a)
#pragma unroll
    for (int b2 = 0; b2 < 2; ++b2) acc[a][b2] = (f32x4){0.f, 0.f, 0.f, 0.f};

  const int wr = (w >> 1) * 2;
  const int wc = (w & 1) * 2;

  gload16(A + abase + (size_t)kt0 * 512, (void*)&sA[0][w * 512]);
  gload16(BT + bbase + (size_t)kt0 * 512, (void*)&sB[0][w * 512]);
  __syncthreads();

  int cur = 0;
  for (int ti = 0; ti < ktiles; ++ti) {
    if (ti + 1 < ktiles) {
      gload16(A + abase + (size_t)(kt0 + ti + 1) * 512, (void*)&sA[cur ^ 1][w * 512]);
      gload16(BT + bbase + (size_t)(kt0 + ti + 1) * 512, (void*)&sB[cur ^ 1][w * 512]);
    }

    half8 a[2], b[2];
#pragma unroll
    for (int i = 0; i < 2; ++i) {
      a[i] = *(const half8*)&sA[cur][(wr + i) * 512 + l * 8];
      b[i] = *(const half8*)&sB[cur][(wc + i) * 512 + l * 8];
    }
#pragma unroll
    for (int mt = 0; mt < 2; ++mt)
#pragma unroll
      for (int nt2 = 0; nt2 < 2; ++nt2)
        acc[mt][nt2] = __builtin_amdgcn_mfma_f32_16x16x32_f16(a[mt], b[nt2], acc[mt][nt2], 0, 0, 0);
    __syncthreads();
    cur ^= 1;
  }

  const int rowb = row0 + (w >> 1) * 32;
  const int colb = col0 + (w & 1) * 32;
#pragma unroll
  for (int mt = 0; mt < 2; ++mt)
#pragma unroll
    for (int nt2 = 0; nt2 < 2; ++nt2) {
      const int col = colb + nt2 * 16 + lr;
#pragma unroll
      for (int j = 0; j < 4; ++j) {
        const int row = rowb + mt * 16 + lc * 4 + j;
        float v = acc[mt][nt2][j];
        if (mode == 0) {
          Of[(size_t)obz * M * N + (size_t)row * N + col] = v;
        } else if (mode == 2) {
          const size_t frag = (size_t)(row >> 4) * (N >> 5) + (col >> 5);
          const size_t dst = (size_t)br * M * N + frag * 512 +
                             (((col >> 3) & 3) * 16 + (row & 15)) * 8 + (col & 7);
          Ob[dst] = f2h(v * oscale);
        } else {  // mode 3: kv -> kf / vf fragment layouts
          const u16 hv = f2h(v);
          if (col < 512) {
            const int h = col >> 6, d = col & 63;
            const size_t dst = (size_t)br * 524288 + (size_t)h * 65536 +
                ((size_t)(row >> 4) * 2 + (d >> 5)) * 512 +
                ((row & 15) + 16 * ((d >> 3) & 3)) * 8 + (d & 7);
            Okf[dst] = hv;
          } else {
            const int c = col - 512;
            const int h = c >> 6, d = c & 63;
            const size_t dst = (size_t)br * 524288 + (size_t)h * 65536 +
                ((size_t)(row >> 5) * 4 + (d >> 4)) * 512 +
                ((d & 15) + 16 * ((row >> 3) & 3)) * 8 + (row & 7);
            Ovf[dst] = hv;
          }
        }
      }
    }
}

// ==================== gemm_sp kernel (kv projection) ====================
__global__ __launch_bounds__(256) void gemm_sp(
    const u16* __restrict__ A0, const u16* __restrict__ A1,
    const u16* __restrict__ BT,
    int M, int N, int Kf, int ktiles, int nk, int mode,
    float* __restrict__ Of, u16* __restrict__ Ob,
    u16* __restrict__ Okf, u16* __restrict__ Ovf, float oscale) {
  __shared__ u16 sA[2][2048], sB[2][2048];
  const int nwx = gridDim.x, nwy = gridDim.y;
  const int total = nwx * nwy * gridDim.z;
  const int L = blockIdx.x + nwx * (blockIdx.y + nwy * blockIdx.z);
  const int chunk = total >> 3;
  int W = (L & 7) * chunk + (L >> 3);
  const int wx = W % nwx; W /= nwx;
  const int wy = W % nwy;
  const int bz = W / nwy;
  const int br = bz / nk, kcid = bz % nk;
  gemm_body(br ? A1 : A0, BT, Kf, ktiles, kcid * ktiles, wy * 64, wx * 64,
            mode, M, N, bz, br, Of, Ob, Okf, Ovf, oscale, sA, sB);
}

// ==================== fused conv (split-K=4) + qproj (one launch; outputs DISJOINT) ====================
__global__ __launch_bounds__(256) void qc_fused(
    const u16* __restrict__ xc, const u16* __restrict__ W2Tp,
    const u16* __restrict__ xq, const u16* __restrict__ WqTp,
    float* __restrict__ xr, u16* __restrict__ qb2, float qscale) {
  __shared__ u16 sA[2][2048], sB[2][2048];
  if (blockIdx.x < 1024) {
    // SR conv as packed GEMM, split-K=4 -> f32 partials
    const int L = blockIdx.x;
    int W = (L & 7) * 128 + (L >> 3);
    const int wx = W % 8; W /= 8;
    const int wy = W % 16;
    const int bz = W / 16;           // br*4 + kcid
    const int br = bz >> 2, kcid = bz & 3;
    gemm_body(br ? xc + 2097152 : xc, W2Tp, 64, 16, kcid * 16, wy * 64, wx * 64,
              0, 1024, 512, bz, br, xr, nullptr, nullptr, nullptr, 1.0f, sA, sB);
  } else {
    // q projection -> FRAG-PACKED fp16 q (pre-scaled)
    const int L = blockIdx.x - 1024;
    int W = (L & 7) * 128 + (L >> 3);
    const int wx = W % 8; W /= 8;
    const int wy = W % 64;
    const int br = W / 64;
    gemm_body(br ? xq + 2097152 : xq, WqTp, 16, 16, 0, wy * 64, wx * 64,
              2, 4096, 512, br, br, nullptr, qb2, nullptr, nullptr, qscale, sA, sB);
  }
}

// ==================== out-proj + bias + mask + predicated token exchange ====================
// One branch per block (1024 blocks, 16 KB LDS, 4 blocks/CU). Each output element
// has exactly one writer:
//   out_b[row]     <- branch-b block where mask_b >= thr
//   out_{1-b}[row] <- branch-b block where mask_{1-b} < thr
__global__ __launch_bounds__(256) void gemm_out(
    const u16* __restrict__ Ap, const u16* __restrict__ Bp,
    const float* __restrict__ bias,
    const float* __restrict__ mask0, const float* __restrict__ mask1,
    float* __restrict__ out) {
  __shared__ u16 sA[2][2048], sB[2][2048];
  const int t = threadIdx.x;
  const int w = t >> 6;
  const int l = t & 63;
  const int lr = l & 15;
  const int lc = l >> 4;

  // XCD swizzle over (8,64,2) = 1024 blocks
  const int L = blockIdx.x + 8 * (blockIdx.y + 64 * blockIdx.z);
  int W = (L & 7) * 128 + (L >> 3);
  const int wx = W % 8; W /= 8;
  const int wy = W % 64;
  const int br = W / 64;

  const int row0 = wy * 64;
  const int col0 = wx * 64;
  const int Kf = 16;
  const u16* A = Ap + (size_t)br * 2097152;

  const size_t abase = (size_t)((row0 >> 4) + w) * Kf * 512 + (size_t)l * 8;
  const size_t bbase = (size_t)((col0 >> 4) + w) * Kf * 512 + (size_t)l * 8;

  f32x4 acc[2][2];
#pragma unroll
  for (int a = 0; a < 2; ++a)
#pragma unroll
    for (int b2 = 0; b2 < 2; ++b2) acc[a][b2] = (f32x4){0.f, 0.f, 0.f, 0.f};

  const int wr = (w >> 1) * 2;
  const int wc = (w & 1) * 2;

  gload16(A + abase, (void*)&sA[0][w * 512]);
  gload16(Bp + bbase, (void*)&sB[0][w * 512]);
  __syncthreads();

  int cur = 0;
  for (int ti = 0; ti < 16; ++ti) {
    if (ti + 1 < 16) {
      gload16(A + abase + (size_t)(ti + 1) * 512, (void*)&sA[cur ^ 1][w * 512]);
      gload16(Bp + bbase + (size_t)(ti + 1) * 512, (void*)&sB[cur ^ 1][w * 512]);
    }
    half8 a[2], b[2];
#pragma unroll
    for (int i = 0; i < 2; ++i) {
      a[i] = *(const half8*)&sA[cur][(wr + i) * 512 + l * 8];
      b[i] = *(const half8*)&sB[cur][(wc + i) * 512 + l * 8];
    }
#pragma unroll
    for (int mt = 0; mt < 2; ++mt)
#pragma unroll
      for (int nt2 = 0; nt2 < 2; ++nt2)
        acc[mt][nt2] = __builtin_amdgcn_mfma_f32_16x16x32_f16(a[mt], b[nt2], acc[mt][nt2], 0, 0, 0);
    __syncthreads();
    cur ^= 1;
  }

  const float* mk = br ? mask1 : mask0;   // own mask
  const float* mo = br ? mask0 : mask1;   // other branch's mask
  float* myout = out + (size_t)br * 2097152;
  float* otout = out + (size_t)(br ^ 1) * 2097152;

  const int rowb = row0 + (w >> 1) * 32;
  const int colb = col0 + (w & 1) * 32;
#pragma unroll
  for (int mt = 0; mt < 2; ++mt)
#pragma unroll
    for (int nt2 = 0; nt2 < 2; ++nt2) {
      const int col = colb + nt2 * 16 + lr;
      const float bv = bias[col];
#pragma unroll
      for (int j = 0; j < 4; ++j) {
        const int row = rowb + mt * 16 + lc * 4 + j;
        const float mv = mk[row];
        const float o = (acc[mt][nt2][j] + bv) * mv;
        if (mv >= 0.02f) myout[(size_t)row * 512 + col] = o;
        if (mo[row] < 0.02f) otout[(size_t)row * 512 + col] = o;
      }
    }
}

// ==================== LayerNorm: sum 4 conv partials + bsr -> frag-packed fp16 ====================
__global__ __launch_bounds__(256) void ln_split(const float* __restrict__ xr,
                                                const float* __restrict__ bsr,
                                                const float* __restrict__ gamma,
                                                const float* __restrict__ beta,
                                                u16* __restrict__ xnp) {
  const int row = blockIdx.x;
  const int br = blockIdx.y;
  const int t = threadIdx.x;
  const float* p = xr + (size_t)br * 4 * 524288 + (size_t)row * 512;
  const int c = t * 2;
  float v0 = p[c] + p[524288 + c] + p[1048576 + c] + p[1572864 + c] + bsr[c];
  float v1 = p[c + 1] + p[524288 + c + 1] + p[1048576 + c + 1] + p[1572864 + c + 1] + bsr[c + 1];
  float s = v0 + v1, sq = v0 * v0 + v1 * v1;
#pragma unroll
  for (int m = 1; m < 64; m <<= 1) {
    s += __shfl_xor(s, m, 64);
    sq += __shfl_xor(sq, m, 64);
  }
  __shared__ float ls[4], lsq[4];
  __shared__ float ybuf[512];
  if ((t & 63) == 0) { ls[t >> 6] = s; lsq[t >> 6] = sq; }
  __syncthreads();
  s = ls[0] + ls[1] + ls[2] + ls[3];
  sq = lsq[0] + lsq[1] + lsq[2] + lsq[3];
  float mean = s * (1.0f / 512.0f);
  float var = sq * (1.0f / 512.0f) - mean * mean;
  float rs = rsqrtf(var + 1e-5f);
  ybuf[c] = (v0 - mean) * rs * gamma[c] + beta[c];
  ybuf[c + 1] = (v1 - mean) * rs * gamma[c + 1] + beta[c + 1];
  __syncthreads();
  if (t < 64) {
    const int c0 = t * 8;
    const int kt = c0 >> 5, lcf = (c0 >> 3) & 3, lrf = row & 15;
    const size_t dst = (size_t)br * 524288 +
        ((size_t)(row >> 4) * 16 + kt) * 512 + (lcf * 16 + lrf) * 8;
    short8 o8;
#pragma unroll
    for (int j = 0; j < 8; ++j) o8[j] = (short)f2h(ybuf[c0 + j]);
    *(short8*)&xnp[dst] = o8;
  }
}

// ==================== fp16 MFMA flash attention (64 q/block, 4-way KV split) ====================
// qb FRAG-PACKED (Kf=16). kf/vf fragment layouts. Output FRAG-PACKED fp16.
// Wave w handles kv slice [w*256, w*256+256) for all 64 q; linear partials
// combine in LDS via two d-half passes (no max tracking, p = 2^s).
__global__ __launch_bounds__(256) void attn_mfma(const u16* __restrict__ qb,
                                                 const u16* __restrict__ kf,
                                                 const u16* __restrict__ vf,
                                                 u16* __restrict__ aop) {
  const int t = threadIdx.x;
  const int w = t >> 6;
  const int l = t & 63;
  const int lr = l & 15;
  const int lc = l >> 4;
  const int hh = blockIdx.y;
  const int n0 = blockIdx.x * 64;
  const int br = blockIdx.z;
  qb += (size_t)br * 2097152;
  kf += (size_t)br * 524288 + (size_t)hh * 65536;
  vf += (size_t)br * 524288 + (size_t)hh * 65536;
  aop += (size_t)br * 2097152;

  // union: P [4 waves][64 q][72 kv] u16 (loop) / Osum [4][32 d][66 q] f32 (combine pass)
  __shared__ __align__(16) u16 SH[18944];          // 37888 B
  u16* Pw = &SH[w * 4608];
  float* Osum = (float*)SH;                         // 33792 B per pass
  float* Lsum = (float*)(SH + 18432);               // byte 36864, [4][64] f32

  // Q^T B-fragments: frag = ((n0>>4)+qh)*16 + hh*2 + ks
  half8 bq[4][2];
#pragma unroll
  for (int qh = 0; qh < 4; ++qh)
#pragma unroll
    for (int ks = 0; ks < 2; ++ks)
      bq[qh][ks] = *(const half8*)&qb[
          (size_t)(((n0 >> 4) + qh) * 16 + hh * 2 + ks) * 512 + l * 8];

  f32x4 acc[4][4];   // [db][qh]
#pragma unroll
  for (int a = 0; a < 4; ++a)
#pragma unroll
    for (int b = 0; b < 4; ++b) acc[a][b] = (f32x4){0.f, 0.f, 0.f, 0.f};
  float lsum[4] = {0.f, 0.f, 0.f, 0.f};

  for (int it = 0; it < 4; ++it) {
    const int m0 = w * 256 + it * 64;
    const u16* ktile = kf + (size_t)(m0 >> 4) * 1024;
    const u16* vtile = vf + (size_t)(m0 >> 5) * 2048;

    half8 kc[8];
#pragma unroll
    for (int f = 0; f < 8; ++f)
      kc[f] = *(const half8*)&ktile[(size_t)f * 512 + l * 8];

#pragma unroll
    for (int f = 0; f < 4; ++f) {
      f32x4 st[4];
      __builtin_amdgcn_s_setprio(1);
#pragma unroll
      for (int qh = 0; qh < 4; ++qh) {
        f32x4 s = (f32x4){0.f, 0.f, 0.f, 0.f};
        s = __builtin_amdgcn_mfma_f32_16x16x32_f16(kc[f * 2 + 0], bq[qh][0], s, 0, 0, 0);
        s = __builtin_amdgcn_mfma_f32_16x16x32_f16(kc[f * 2 + 1], bq[qh][1], s, 0, 0, 0);
        st[qh] = s;
      }
      __builtin_amdgcn_s_setprio(0);
#pragma unroll
      for (int qh = 0; qh < 4; ++qh) {
        float p0, p1, p2, p3;
        asm("v_exp_f32 %0, %1" : "=v"(p0) : "v"(st[qh][0]));
        asm("v_exp_f32 %0, %1" : "=v"(p1) : "v"(st[qh][1]));
        asm("v_exp_f32 %0, %1" : "=v"(p2) : "v"(st[qh][2]));
        asm("v_exp_f32 %0, %1" : "=v"(p3) : "v"(st[qh][3]));
        lsum[qh] += (p0 + p1) + (p2 + p3);
        auto ha = __builtin_amdgcn_cvt_pkrtz(p0, p1);
        auto hb = __builtin_amdgcn_cvt_pkrtz(p2, p3);
        uint2 pk; pk.x = __builtin_bit_cast(u32, ha); pk.y = __builtin_bit_cast(u32, hb);
        *(uint2*)&Pw[(qh * 16 + lr) * 72 + f * 16 + lc * 4] = pk;
      }
    }

    half8 av[8];
#pragma unroll
    for (int f = 0; f < 8; ++f)
      av[f] = *(const half8*)&vtile[(size_t)f * 512 + l * 8];

#pragma unroll
    for (int ks = 0; ks < 2; ++ks) {
#pragma unroll
      for (int qh = 0; qh < 4; ++qh) {
        half8 bp = *(const half8*)&Pw[(qh * 16 + lr) * 72 + ks * 32 + lc * 8];
        __builtin_amdgcn_s_setprio(1);
#pragma unroll
        for (int db = 0; db < 4; ++db)
          acc[db][qh] = __builtin_amdgcn_mfma_f32_16x16x32_f16(av[ks * 4 + db], bp, acc[db][qh], 0, 0, 0);
        __builtin_amdgcn_s_setprio(0);
      }
    }
  }

#pragma unroll
  for (int qh = 0; qh < 4; ++qh) {
    lsum[qh] += __shfl_xor(lsum[qh], 16, 64);
    lsum[qh] += __shfl_xor(lsum[qh], 32, 64);
  }

  // two-pass combine over d halves (Osum overlays P; Lsum is above Osum region)
#pragma unroll
  for (int pass = 0; pass < 2; ++pass) {
    __syncthreads();   // P reads (or prev pass combine reads) done
#pragma unroll
    for (int db2 = 0; db2 < 2; ++db2) {
      const int db = pass * 2 + db2;
#pragma unroll
      for (int qh = 0; qh < 4; ++qh)
#pragma unroll
        for (int j = 0; j < 4; ++j)
          Osum[((size_t)w * 32 + db2 * 16 + lc * 4 + j) * 66 + (qh * 16 + lr)] = acc[db][qh][j];
    }
    if (pass == 0 && lc == 0) {
#pragma unroll
      for (int qh = 0; qh < 4; ++qh) Lsum[w * 64 + qh * 16 + lr] = lsum[qh];
    }
    __syncthreads();

    const int q = t & 63;
    const int dd = (t >> 6) * 8;    // 8 d per thread within pass
    const float linv = 1.0f / (Lsum[q] + Lsum[64 + q] + Lsum[128 + q] + Lsum[192 + q]);
    short8 hv;
#pragma unroll
    for (int i = 0; i < 8; ++i) {
      const int drow = dd + i;
      float v = (Osum[drow * 66 + q] + Osum[(32 + drow) * 66 + q] +
                 Osum[(64 + drow) * 66 + q] + Osum[(96 + drow) * 66 + q]) * linv;
      hv[i] = (short)f2h(v);
    }
    const int mrow = n0 + q;
    const int kcoord = hh * 64 + pass * 32 + dd;
    const size_t dst = ((size_t)(mrow >> 4) * 16 + (kcoord >> 5)) * 512 +
                       (((kcoord >> 3) & 3) * 16 + (mrow & 15)) * 8;
    *(short8*)&aop[dst] = hv;
  }
}

extern "C" void kernel_launch(void* const* d_in, const int* in_sizes, int n_in,
                              void* d_out, int out_size, void* d_ws, size_t ws_size,
                              hipStream_t stream) {
  const float* x0    = (const float*)d_in[0];
  const float* x1    = (const float*)d_in[1];
  const float* mask0 = (const float*)d_in[2];
  const float* mask1 = (const float*)d_in[3];
  const float* Wq    = (const float*)d_in[4];
  const float* Wkv   = (const float*)d_in[5];
  const float* Wsr   = (const float*)d_in[6];
  const float* bsr   = (const float*)d_in[7];
  const float* gamma = (const float*)d_in[8];
  const float* beta  = (const float*)d_in[9];
  const float* Wp    = (const float*)d_in[10];
  const float* bp    = (const float*)d_in[11];

  u16* U = (u16*)d_ws;
  u16* WqTp  = U;                      // 262144
  u16* WkvTp = WqTp + 262144;          // 524288
  u16* WpTp  = WkvTp + 524288;         // 262144
  u16* W2Tp  = WpTp + 262144;          // 1048576
  u16* xq    = W2Tp + 1048576;         // 4194304 (2 br, stride 2097152)
  u16* xc    = xq + 4194304;           // 4194304 (2 br; xn reuses [0,1048576) after conv)
  u16* R     = xc + 4194304;           // xr f32 region
  float* xr  = (float*)R;              // 4194304 f32 (2 br x 4 parts x 524288)
  u16* qb2   = R + 8388608;            // 4194304 — DISJOINT from xr (qc_fused concurrent)
  u16* kf    = qb2 + 4194304;          // 1048576 (2 br, stride 524288)
  u16* vf    = kf + 1048576;           // 1048576
  u16* aop   = xq;                     // alias (xq dead after qproj)

  float* out = (float*)d_out;
  dim3 blk(256);

  // fragment-packing prep (weights + x in q-proj and conv-gather orders)
  prep_pack<<<5120, blk, 0, stream>>>(Wq, Wkv, Wp, Wsr, x0, x1,
      WqTp, WkvTp, WpTp, W2Tp, xq, xc);

  // fused: SR conv (split-K=4 -> f32 partials) + q projection (frag-packed fp16)
  qc_fused<<<2048, blk, 0, stream>>>(xc, W2Tp, xq, WqTp, xr, qb2,
      0.125f * 1.4426950408889634f);

  // LayerNorm (+bsr) -> frag-packed fp16 into xc (conv input dead)
  ln_split<<<dim3(1024, 2), blk, 0, stream>>>(xr, bsr, gamma, beta, xc);

  // kv projection -> kf/vf fragment layouts DIRECTLY
  gemm_sp<<<dim3(16, 16, 2), blk, 0, stream>>>(xc, xc + 524288, WkvTp,
      1024, 1024, 16, 16, 1, 3, nullptr, nullptr, kf, vf, 1.0f);

  // attention (64 q/block, 4-way KV split) -> aop frag-packed
  attn_mfma<<<dim3(64, 8, 2), blk, 0, stream>>>(qb2, kf, vf, aop);

  // out-proj + bias + mask + predicated token exchange (1 branch/block, 1024 blocks)
  gemm_out<<<dim3(8, 64, 2), blk, 0, stream>>>(aop, WpTp, bp, mask0, mask1, out);
}